// Round 7
// baseline (3402.491 us; speedup 1.0000x reference)
//
#include <hip/hip_runtime.h>

// ---------------------------------------------------------------------------
// Seq2Seq LSTM (B=16, H=256, L=2, S=128, T=128, V=32000).
// v5c: FOUR dispatches: memset(poison) -> prep -> mega -> logits_gemm.
// mega = pipelined 4-layer LSTM (64 blocks) + ep/dp projections (64 blocks)
// + ctx (16 blocks), all overlapped via data-is-flag sentinel sync.
//
// v5c fix vs v5b: long-wait polls are TWO-PHASE to kill coherence-point
// congestion (v5b: 80 waiter blocks x 256 threads x 16-word sweeps at
// s_sleep(1) ~= 30-50 atomic loads/cycle -> 4.4x lstm slowdown).
//  phase 1 (coarse gate): tid==0 polls ONE matched-producer word at
//    s_sleep(32/64) (~1.5-3us period) -> __syncthreads().
//  phase 2: full per-word validation (unchanged POLLCOLs, now ~1 sweep).
// Critical-path polls (own-h recurrence, prev-layer x) stay at s_sleep(1).
// Correctness unchanged: gates are heuristic throttles only; every word a
// consumer reads is still directly validated by its block afterward.
// ---------------------------------------------------------------------------

typedef __attribute__((ext_vector_type(8))) short s8v;
typedef __attribute__((ext_vector_type(8))) __bf16 bf8v;
typedef __attribute__((ext_vector_type(4))) float f4v;

#define HDIM 256
#define DLEN 127
#define NVOC 32000
#define SENTINEL 0xFFFFFFFFu

__device__ __forceinline__ float bf2f(unsigned short u) {
  union { unsigned int i; float f; } v; v.i = ((unsigned int)u) << 16; return v.f;
}
__device__ __forceinline__ unsigned short f2bf(float x) {
  union { float f; unsigned int i; } v; v.f = x;
  unsigned int u = v.i;
  return (unsigned short)((u + 0x7FFFu + ((u >> 16) & 1u)) >> 16);
}
__device__ __forceinline__ float sigm(float x) {
  x = fminf(fmaxf(x, -30.f), 30.f);
  return 1.f / (1.f + __expf(-x));
}
__device__ __forceinline__ float tanh_f(float x) {
  float y = fminf(fmaxf(x, -15.f), 15.f);
  float e = __expf(2.f * y);
  return (e - 1.f) / (e + 1.f);
}
__device__ __forceinline__ f4v mfma_bf16(s8v a, s8v b, f4v c) {
  return __builtin_amdgcn_mfma_f32_16x16x32_bf16(
      __builtin_bit_cast(bf8v, a), __builtin_bit_cast(bf8v, b), c, 0, 0, 0);
}

// full validation poll: 16 rows x stride-256 words at column tid (tight)
#define POLLCOL(base)                                                         \
  for (;;) {                                                                  \
    bool ok = true;                                                           \
    _Pragma("unroll") for (int i_ = 0; i_ < 16; i_++)                         \
        uv[i_] = __hip_atomic_load((base) + i_ * 256 + tid, __ATOMIC_RELAXED, \
                                   __HIP_MEMORY_SCOPE_AGENT);                 \
    _Pragma("unroll") for (int i_ = 0; i_ < 16; i_++)                         \
        ok &= (uv[i_] != SENTINEL);                                           \
    if (ok) break;                                                            \
    __builtin_amdgcn_s_sleep(1);                                              \
  }

// coarse gate: tid==0 polls one word at low rate; barrier releases the block
#define COARSE_GATE(probeptr, slp)                                            \
  if (tid == 0) {                                                             \
    while (__hip_atomic_load((probeptr), __ATOMIC_RELAXED,                    \
                             __HIP_MEMORY_SCOPE_AGENT) == SENTINEL)           \
      __builtin_amdgcn_s_sleep(slp);                                          \
  }                                                                           \
  __syncthreads();

// ---------------- fused preprocessing ----------------
// grid 9228: [0,4096) Whh hi/lo split; [4096,8192) Wih bf16; [8192,8208)
// bias sums; [8208,8720) enc gather (4 rows/block); [8720,9228) dec gather.
__global__ __launch_bounds__(256) void prep(
    const float* __restrict__ W5, const float* __restrict__ W9,
    const float* __restrict__ W13, const float* __restrict__ W17,
    const float* __restrict__ W4, const float* __restrict__ W8,
    const float* __restrict__ W12, const float* __restrict__ W16,
    const float* __restrict__ b6, const float* __restrict__ b7,
    const float* __restrict__ b10, const float* __restrict__ b11,
    const float* __restrict__ b14, const float* __restrict__ b15,
    const float* __restrict__ b18, const float* __restrict__ b19,
    const int* __restrict__ src, const int* __restrict__ tgt,
    const float* __restrict__ enc_emb, const float* __restrict__ dec_emb,
    unsigned short* __restrict__ WHB, unsigned short* __restrict__ WIB,
    float* __restrict__ bsum,
    unsigned short* __restrict__ Xe, unsigned short* __restrict__ Xd) {
  int blk = blockIdx.x, tid = threadIdx.x;
  if (blk < 4096) {
    int l = blk >> 10;
    int i = (blk & 1023) * 256 + tid;
    const float* W = (l == 0) ? W5 : (l == 1) ? W9 : (l == 2) ? W13 : W17;
    float w = W[i];
    unsigned short h = f2bf(w);
    unsigned short* Hh = WHB + (size_t)l * 524288;
    Hh[i] = h;
    Hh[262144 + i] = f2bf(w - bf2f(h));
  } else if (blk < 8192) {
    int l = (blk - 4096) >> 10;
    int i = ((blk - 4096) & 1023) * 256 + tid;
    const float* W = (l == 0) ? W4 : (l == 1) ? W8 : (l == 2) ? W12 : W16;
    WIB[(size_t)l * 262144 + i] = f2bf(W[i]);
  } else if (blk < 8208) {
    int i = (blk - 8192) * 256 + tid;
    int l = i >> 10, n = i & 1023;
    const float* bi = (l == 0) ? b6 : (l == 1) ? b10 : (l == 2) ? b14 : b18;
    const float* bh = (l == 0) ? b7 : (l == 1) ? b11 : (l == 2) ? b15 : b19;
    bsum[i] = bi[n] + bh[n];
  } else if (blk < 8720) {
    int r = (blk - 8208) * 4 + (tid >> 6);
    int lane = tid & 63;
    int token = src[r];
    float4 v = *(const float4*)&enc_emb[(size_t)token * HDIM + lane * 4];
    unsigned short q[4] = {f2bf(v.x), f2bf(v.y), f2bf(v.z), f2bf(v.w)};
    *(uint2*)&Xe[(size_t)r * HDIM + lane * 4] = *(uint2*)q;
  } else {
    int r = (blk - 8720) * 4 + (tid >> 6);
    int lane = tid & 63;
    int token = tgt[(r / DLEN) * 128 + (r % DLEN)];
    float4 v = *(const float4*)&dec_emb[(size_t)token * HDIM + lane * 4];
    unsigned short q[4] = {f2bf(v.x), f2bf(v.y), f2bf(v.z), f2bf(v.w)};
    *(uint2*)&Xd[(size_t)r * HDIM + lane * 4] = *(uint2*)q;
  }
}

// ---------------- mega: pipelined 4-layer LSTM + attention ----------------
// grid 256. Roles:
//  widx<128 && (widx&7)<4  -> lstm worker: layer=widx&7 (XCD l), blk=widx>>3.
//  else pool p: [0,32) ep-proj tile, [32,64) dp-proj tile, [64,80) ctx worker
//  (b = p-64), [80,192) exit.
__global__ __launch_bounds__(256) void mega(
    const unsigned short* __restrict__ WIB,   // [4][1024][256] bf16
    const unsigned short* __restrict__ WHB,   // [4][hi|lo 262144 each]
    const float* __restrict__ bsum,           // [4][1024]
    const unsigned short* __restrict__ Xe,    // [16*128][256] bf16
    const unsigned short* __restrict__ Xd,    // [16*127][256] bf16
    unsigned int* __restrict__ hsA,           // [4][Tl][16][256] packed hi|lo
    unsigned int* __restrict__ cfinA,         // [2][4096] fp32 bits, poisoned
    float* __restrict__ dpf,                  // [2032][256] fp32, poisoned
    float* __restrict__ epf,                  // [2048][256] fp32, poisoned
    const float* __restrict__ attnW,          // [256][512]
    const float* __restrict__ attnB,          // [256]
    const float* __restrict__ vw,             // [256]
    unsigned short* __restrict__ Acat) {      // [2032][512]
  __shared__ unsigned long long ldsraw[3840];   // 30720 B shared by roles
  int widx = (int)blockIdx.x, tid = threadIdx.x;
  int lane = tid & 63;
  int r16 = lane & 15, kg = lane >> 4;

  if (widx < 128 && (widx & 7) < 4) {
    // ======================= LSTM role (as v4) =======================
    int layer = widx & 7;
    int blk = widx >> 3;
    unsigned short* xx = (unsigned short*)ldsraw;    // 16*264
    unsigned short* hh = xx + 4224;
    unsigned short* hl = hh + 4224;
    float* gbuf = (float*)(hl + 4224);               // [4][16][16]
    int gate = tid >> 6;
    int U = blk * 16;
    int Tl = (layer < 2) ? 128 : 127;
    unsigned int* own = hsA + (size_t)layer * 524288;
    const unsigned int* prevb = (layer & 1) ? own - 524288 : nullptr;
    const unsigned short* Xg = (layer == 0) ? Xe : (layer == 2) ? Xd : nullptr;
    const unsigned int* hini =
        (layer >= 2) ? hsA + (size_t)(layer - 2) * 524288 + (size_t)127 * 4096
                     : nullptr;
    unsigned int* cini = (layer >= 2) ? cfinA + (size_t)(layer - 2) * 4096
                                      : nullptr;
    unsigned int* cout = (layer < 2) ? cfinA + (size_t)layer * 4096 : nullptr;
    unsigned short* hout = (layer == 3) ? Acat : nullptr;

    s8v wfi[8], wfh[8], wfl[8];
    {
      const unsigned short* wi = WIB + (size_t)layer * 262144;
      const unsigned short* wh = WHB + (size_t)layer * 524288;
      const unsigned short* wl = wh + 262144;
      long roff = (long)(gate * 256 + U + r16) * 256 + kg * 8;
      for (int kt = 0; kt < 8; kt++) {
        wfi[kt] = *(const s8v*)(wi + roff + kt * 32);
        wfh[kt] = *(const s8v*)(wh + roff + kt * 32);
        wfl[kt] = *(const s8v*)(wl + roff + kt * 32);
      }
    }
    int b = tid >> 4, u = tid & 15;
    float bb0 = bsum[layer * 1024 + U + u];
    float bb1 = bsum[layer * 1024 + 256 + U + u];
    float bb2 = bsum[layer * 1024 + 512 + U + u];
    float bb3 = bsum[layer * 1024 + 768 + U + u];
    float c;
    if (cini) {
      // long wait (whole enc phase): coarse gate, then per-thread validate
      COARSE_GATE(cini + U, 64)
      unsigned int cw;
      for (;;) {
        cw = __hip_atomic_load(cini + b * 256 + U + u, __ATOMIC_RELAXED,
                               __HIP_MEMORY_SCOPE_AGENT);
        if (cw != SENTINEL) break;
        __builtin_amdgcn_s_sleep(4);
      }
      union { unsigned int i; float f; } cv; cv.i = cw; c = cv.f;
    } else {
      c = 0.f;
    }

    for (int t = 0; t < Tl; t++) {
      unsigned int uv[16];
      unsigned short xr[16];
      if (Xg) {
#pragma unroll
        for (int i = 0; i < 16; i++)
          xr[i] = Xg[((size_t)(i * Tl + t)) * 256 + tid];
      }
      const unsigned int* hbase = (t > 0) ? own + (size_t)(t - 1) * 4096 : hini;
      if (hbase) {
        if (t == 0) { COARSE_GATE(hbase + U, 32) }  // dec init: long wait
        POLLCOL(hbase)
#pragma unroll
        for (int i = 0; i < 16; i++) {
          hh[i * 264 + tid] = (unsigned short)(uv[i] >> 16);
          hl[i * 264 + tid] = (unsigned short)(uv[i] & 0xFFFFu);
        }
      } else {
#pragma unroll
        for (int i = 0; i < 16; i++) { hh[i * 264 + tid] = 0; hl[i * 264 + tid] = 0; }
      }
      if (Xg) {
#pragma unroll
        for (int i = 0; i < 16; i++) xx[i * 264 + tid] = xr[i];
      } else {
        POLLCOL(prevb + (size_t)t * 4096)
#pragma unroll
        for (int i = 0; i < 16; i++)
          xx[i * 264 + tid] = (unsigned short)(uv[i] >> 16);
      }
      __syncthreads();
      f4v a0 = (f4v){0.f, 0.f, 0.f, 0.f};
      f4v a1 = a0, a2 = a0, a3 = a0;
#pragma unroll
      for (int kt = 0; kt < 8; kt++) {
        s8v xv = *(const s8v*)&xx[r16 * 264 + kt * 32 + kg * 8];
        s8v ah = *(const s8v*)&hh[r16 * 264 + kt * 32 + kg * 8];
        s8v al = *(const s8v*)&hl[r16 * 264 + kt * 32 + kg * 8];
        a3 = mfma_bf16(xv, wfi[kt], a3);
        a0 = mfma_bf16(ah, wfh[kt], a0);
        a1 = mfma_bf16(al, wfh[kt], a1);
        a2 = mfma_bf16(ah, wfl[kt], a2);
      }
#pragma unroll
      for (int r = 0; r < 4; r++)
        gbuf[gate * 256 + (kg * 4 + r) * 16 + r16] = a0[r] + a1[r] + a2[r] + a3[r];
      __syncthreads();
      float gi = gbuf[0 * 256 + b * 16 + u] + bb0;
      float gf = gbuf[1 * 256 + b * 16 + u] + bb1;
      float gg = gbuf[2 * 256 + b * 16 + u] + bb2;
      float go = gbuf[3 * 256 + b * 16 + u] + bb3;
      c = sigm(gf) * c + sigm(gi) * tanh_f(gg);
      float h = sigm(go) * tanh_f(c);
      unsigned short hb = f2bf(h);
      unsigned int packed =
          ((unsigned int)hb << 16) | (unsigned int)f2bf(h - bf2f(hb));
      __hip_atomic_store(own + (size_t)t * 4096 + b * 256 + U + u, packed,
                         __ATOMIC_RELAXED, __HIP_MEMORY_SCOPE_AGENT);
      if (hout) hout[(size_t)(b * Tl + t) * 512 + U + u] = hb;
    }
    if (cout) {
      union { float f; unsigned int i; } cv; cv.f = c;
      __hip_atomic_store(cout + b * 256 + U + u, cv.i, __ATOMIC_RELAXED,
                         __HIP_MEMORY_SCOPE_AGENT);
    }
    return;
  }

  int p = (widx < 128) ? ((widx >> 3) * 4 + ((widx & 7) - 4)) : (64 + widx - 128);
  if (p >= 80) return;

  if (p < 64) {
    // ============ projection role: ep (p<32) or dp (p in [32,64)) ============
    int q = (p < 32) ? p : (p - 32);
    int isep = (p < 32) ? 1 : 0;
    int g = q >> 1, n0 = (q & 1) * 128;
    const unsigned int* slab = hsA + (size_t)(isep ? 1 : 3) * 524288;
    int Tl = isep ? 128 : 127;
    const float* Bw = isep ? (attnW + 256) : attnW;     // ldb 512
    int tgate = g * 8 + 7; if (tgate > Tl - 1) tgate = Tl - 1;
    // phase 1: throttled coarse gate on the last-needed step (tid 0 only)
    COARSE_GATE(slab + (size_t)tgate * 4096, 32)
    // phase 2: full validation of every consumed word (fast now)
    for (int k = 0; k < 8; k++) {
      int tt = g * 8 + k;
      if (tt < Tl) {
        unsigned int uv[16];
        POLLCOL(slab + (size_t)tt * 4096)
      }
    }
    __builtin_amdgcn_sched_barrier(0);
    __syncthreads();   // all 256 columns validated before any cross-column read

    unsigned short* As = (unsigned short*)ldsraw;       // 128*40
    unsigned short* Bs = As + 5120;
    int wid = tid >> 6;
    int wm = (wid >> 1) * 64, wn = (wid & 1) * 64;
    f4v acc[4][4];
    for (int i = 0; i < 4; i++)
      for (int j = 0; j < 4; j++) acc[i][j] = (f4v){0.f, 0.f, 0.f, 0.f};

    for (int k0 = 0; k0 < 256; k0 += 32) {
      for (int i = 0; i < 2; i++) {
        int idx = tid + i * 256;
        int row = idx >> 2, kc = (idx & 3) * 8;
        int tt = g * 8 + (row >> 4), bb = row & 15;
        unsigned short qa[8] = {0, 0, 0, 0, 0, 0, 0, 0};
        if (tt < Tl) {
          const unsigned int* wp = slab + (size_t)tt * 4096 + bb * 256 + k0 + kc;
          uint4 w0 = *(const uint4*)wp, w1 = *(const uint4*)(wp + 4);
          qa[0] = (unsigned short)(w0.x >> 16); qa[1] = (unsigned short)(w0.y >> 16);
          qa[2] = (unsigned short)(w0.z >> 16); qa[3] = (unsigned short)(w0.w >> 16);
          qa[4] = (unsigned short)(w1.x >> 16); qa[5] = (unsigned short)(w1.y >> 16);
          qa[6] = (unsigned short)(w1.z >> 16); qa[7] = (unsigned short)(w1.w >> 16);
        }
        *(uint4*)&As[row * 40 + kc] = *(uint4*)qa;
        const float* bp = &Bw[(size_t)(n0 + row) * 512 + k0 + kc];
        float4 b0 = *(const float4*)bp, b1 = *(const float4*)(bp + 4);
        unsigned short qb[8] = {f2bf(b0.x), f2bf(b0.y), f2bf(b0.z), f2bf(b0.w),
                                f2bf(b1.x), f2bf(b1.y), f2bf(b1.z), f2bf(b1.w)};
        *(uint4*)&Bs[row * 40 + kc] = *(uint4*)qb;
      }
      __syncthreads();
      s8v af[4], bfg[4];
      for (int f = 0; f < 4; f++) {
        af[f]  = *(const s8v*)&As[(wm + f * 16 + r16) * 40 + kg * 8];
        bfg[f] = *(const s8v*)&Bs[(wn + f * 16 + r16) * 40 + kg * 8];
      }
      for (int i = 0; i < 4; i++)
        for (int j = 0; j < 4; j++)
          acc[i][j] = mfma_bf16(af[i], bfg[j], acc[i][j]);
      __syncthreads();
    }
    int rbase = kg * 4;
    for (int j = 0; j < 4; j++) {
      int n = n0 + wn + j * 16 + r16;
      float bv = isep ? 0.f : attnB[n];
      for (int i = 0; i < 4; i++) {
        for (int r = 0; r < 4; r++) {
          int m = wm + i * 16 + rbase + r;
          int tt = g * 8 + (m >> 4), bb = m & 15;
          if (tt < Tl) {
            union { float f; unsigned int i; } cv;
            cv.f = acc[i][j][r] + bv;
            float* outb = isep ? epf : dpf;
            size_t row = isep ? (size_t)(bb * 128 + tt) : (size_t)(bb * 127 + tt);
            __hip_atomic_store((unsigned int*)&outb[row * 256 + n], cv.i,
                               __ATOMIC_RELAXED, __HIP_MEMORY_SCOPE_AGENT);
          }
        }
      }
    }
    return;
  }

  // ===================== ctx role: one batch b = p-64 =====================
  {
    int b = p - 64;
    float* sdp = (float*)ldsraw;          // 256
    float* sv  = sdp + 256;               // 256
    float* sc  = sv + 256;                // 128
    sv[tid] = vw[tid];
    const unsigned int* epu = (const unsigned int*)epf;
    // phase 1: coarse gate on the LAST ep row of this batch (tid 0, slow poll)
    COARSE_GATE(epu + (size_t)(b * 128 + 127) * 256, 32)
    // phase 2: full validation of all 128 rows x own column
    for (int c0 = 0; c0 < 128; c0 += 16) {
      unsigned int uv[16];
      POLLCOL(epu + (size_t)(b * 128 + c0) * 256)
    }
    __builtin_amdgcn_sched_barrier(0);
    __syncthreads();   // all columns of ep[b] validated before plain reads
    const unsigned int* dpu = (const unsigned int*)dpf;
    const unsigned int* hs1 = hsA + (size_t)1 * 524288;
    int wid = tid >> 6;
    for (int t = 0; t < DLEN; t++) {
      // coarse gate on dp row t (tid 0, moderate rate), then per-word check
      COARSE_GATE(dpu + (size_t)(b * DLEN + t) * 256, 2)
      unsigned int w;
      const unsigned int* a = dpu + (size_t)(b * DLEN + t) * 256 + tid;
      for (;;) {
        w = __hip_atomic_load(a, __ATOMIC_RELAXED, __HIP_MEMORY_SCOPE_AGENT);
        if (w != SENTINEL) break;
        __builtin_amdgcn_s_sleep(1);
      }
      union { unsigned int i; float f; } cw; cw.i = w;
      sdp[tid] = cw.f;
      __syncthreads();
      for (int i = 0; i < 32; i++) {
        int s = wid * 32 + i;
        float4 e4 = *(const float4*)&epf[(size_t)(b * 128 + s) * 256 + lane * 4];
        int h0 = lane * 4;
        float part = sv[h0] * tanh_f(sdp[h0] + e4.x);
        part += sv[h0 + 1] * tanh_f(sdp[h0 + 1] + e4.y);
        part += sv[h0 + 2] * tanh_f(sdp[h0 + 2] + e4.z);
        part += sv[h0 + 3] * tanh_f(sdp[h0 + 3] + e4.w);
        for (int off = 32; off >= 1; off >>= 1) part += __shfl_xor(part, off);
        if (lane == 0) sc[s] = part;
      }
      __syncthreads();
      if (wid == 0) {
        float s0 = sc[lane], s1 = sc[lane + 64];
        float mx = fmaxf(s0, s1);
        for (int off = 32; off >= 1; off >>= 1) mx = fmaxf(mx, __shfl_xor(mx, off));
        float e0 = __expf(s0 - mx), e1 = __expf(s1 - mx);
        float sm = e0 + e1;
        for (int off = 32; off >= 1; off >>= 1) sm += __shfl_xor(sm, off);
        float inv = 1.0f / sm;
        sc[lane] = e0 * inv;
        sc[lane + 64] = e1 * inv;
      }
      __syncthreads();
      float acc2 = 0.f;
      for (int s = 0; s < 128; s++) {
        unsigned int uvv = hs1[(size_t)s * 4096 + b * 256 + tid];
        float hv = bf2f((unsigned short)(uvv >> 16)) +
                   bf2f((unsigned short)(uvv & 0xFFFFu));
        acc2 += sc[s] * hv;
      }
      Acat[(size_t)(b * DLEN + t) * 512 + 256 + tid] = f2bf(acc2);
      __syncthreads();                  // sc reads done before next overwrite
    }
    return;
  }
}

// ---------------- logits GEMM (+ fused zero_t0) ----------------
// grid (250, 17): y<16 -> 128x128 tile (m0=y*128, n0=x*128), K=512, mode-1
// row mapping (b,t)->b*128+t+1; y==16 -> zero the 16 t=0 rows for this n0.
__global__ __launch_bounds__(256) void logits_gemm(
    const unsigned short* __restrict__ A,     // Acat [2032][512] bf16
    const float* __restrict__ B,              // outW [32000][512] fp32
    const float* __restrict__ bias,           // outB
    float* __restrict__ Cf) {                 // out  [16*128][32000]
  int n0 = blockIdx.x * 128;
  int tid = threadIdx.x;
  if (blockIdx.y == 16) {
    int col = tid & 127;
    for (int b = tid >> 7; b < 16; b += 2)
      Cf[(size_t)b * 128 * NVOC + n0 + col] = 0.f;
    return;
  }
  __shared__ unsigned short As[128 * 40];
  __shared__ unsigned short Bs[128 * 40];
  int lane = tid & 63, wid = tid >> 6;
  int wm = (wid >> 1) * 64, wn = (wid & 1) * 64;
  int r16 = lane & 15, kg = lane >> 4;
  int m0 = blockIdx.y * 128;
  f4v acc[4][4];
  for (int i = 0; i < 4; i++)
    for (int j = 0; j < 4; j++) acc[i][j] = (f4v){0.f, 0.f, 0.f, 0.f};

  for (int k0 = 0; k0 < 512; k0 += 32) {
    for (int i = 0; i < 2; i++) {
      int idx = tid + i * 256;
      int row = idx >> 2, kc = (idx & 3) * 8;
      uint4 va = {0u, 0u, 0u, 0u};
      int gm = m0 + row;
      if (gm < 2032) va = *(const uint4*)&A[(size_t)gm * 512 + k0 + kc];
      *(uint4*)&As[row * 40 + kc] = va;
      const float* bp = &B[(size_t)(n0 + row) * 512 + k0 + kc];
      float4 b0 = *(const float4*)bp, b1 = *(const float4*)(bp + 4);
      unsigned short q[8] = {f2bf(b0.x), f2bf(b0.y), f2bf(b0.z), f2bf(b0.w),
                             f2bf(b1.x), f2bf(b1.y), f2bf(b1.z), f2bf(b1.w)};
      *(uint4*)&Bs[row * 40 + kc] = *(uint4*)q;
    }
    __syncthreads();
    s8v af[4], bfg[4];
    for (int f = 0; f < 4; f++) {
      af[f]  = *(const s8v*)&As[(wm + f * 16 + r16) * 40 + kg * 8];
      bfg[f] = *(const s8v*)&Bs[(wn + f * 16 + r16) * 40 + kg * 8];
    }
    for (int i = 0; i < 4; i++)
      for (int j = 0; j < 4; j++)
        acc[i][j] = mfma_bf16(af[i], bfg[j], acc[i][j]);
    __syncthreads();
  }
  int rbase = kg * 4;
  for (int j = 0; j < 4; j++) {
    int n = n0 + wn + j * 16 + r16;
    float bv = bias[n];
    for (int i = 0; i < 4; i++) {
      for (int r = 0; r < 4; r++) {
        int m = m0 + wm + i * 16 + rbase + r;
        if (m < 2032) {
          int bb = m / DLEN, tt = m - bb * DLEN;
          Cf[(size_t)(bb * 128 + tt + 1) * NVOC + n] = acc[i][j][r] + bv;
        }
      }
    }
  }
}

// ---------------------------------------------------------------------------
extern "C" void kernel_launch(void* const* d_in, const int* in_sizes, int n_in,
                              void* d_out, int out_size, void* d_ws, size_t ws_size,
                              hipStream_t stream) {
  (void)in_sizes; (void)n_in; (void)out_size; (void)ws_size;
  const int* src = (const int*)d_in[0];
  const int* tgt = (const int*)d_in[1];
  auto F32 = [&](int i) { return (const float*)d_in[i]; };
  const float* enc_emb = F32(2);
  const float* dec_emb = F32(3);
  const float* attnW = F32(20);
  const float* attnB = F32(21);
  const float* vw = F32(22);
  const float* outW = F32(23);
  const float* outB = F32(24);
  float* out = (float*)d_out;

  // ---- d_out scratch (dead before logits_gemm writes) ----
  // poison region (one contiguous memset): hsA | dp | ep | cfin
  unsigned int* hsA = (unsigned int*)out;                 // 2,097,152 u32
  float* dpf = (float*)(hsA + 2097152);                   // 520,192 f
  float* epf = dpf + 520192;                              // 524,288 f
  unsigned int* cfinA = (unsigned int*)(epf + 524288);    // 8,192 u32
  // non-poisoned scratch
  unsigned short* WHB = (unsigned short*)(cfinA + 8192);  // 2,097,152 sh
  unsigned short* WIB = WHB + 2097152;                    // 1,048,576 sh
  unsigned short* Xe  = WIB + 1048576;                    // 524,288 sh
  unsigned short* Xd  = Xe + 524288;                      // 520,192 sh
  float* bsum = (float*)(Xd + 520192);                    // 4,096 f
  // total ~21 MB << 262 MB of d_out

  // ---- d_ws: Acat only (live during logits GEMM) ----
  unsigned short* Acat = (unsigned short*)d_ws;           // 2,080,768 B

  size_t poisonB = (size_t)(2097152 + 520192 + 524288 + 8192) * 4;
  hipMemsetAsync(hsA, 0xFF, poisonB, stream);
  prep<<<9228, 256, 0, stream>>>(
      F32(5), F32(9), F32(13), F32(17),
      F32(4), F32(8), F32(12), F32(16),
      F32(6), F32(7), F32(10), F32(11),
      F32(14), F32(15), F32(18), F32(19),
      src, tgt, enc_emb, dec_emb,
      WHB, WIB, bsum, Xe, Xd);
  mega<<<256, 256, 0, stream>>>(WIB, WHB, bsum, Xe, Xd, hsA, cfinA,
                                dpf, epf, attnW, attnB, vw, Acat);
  // ---- final writes: every element of d_out overwritten from here ----
  logits_gemm<<<dim3(250, 17), 256, 0, stream>>>(Acat, outW, outB, out);
}

// Round 8
// 1255.073 us; speedup vs baseline: 2.7110x; 2.7110x over previous
//
#include <hip/hip_runtime.h>

// ---------------------------------------------------------------------------
// Seq2Seq LSTM (B=16, H=256, L=2, S=128, T=128, V=32000).
// v6: FIVE dispatches:
//   memset(poison hsA+cfin) -> prep -> lstm_pipe(+ep/dp projections as
//   per-layer epilogues) -> attn_ctx -> logits_gemm(+zero_t0).
// Reverts v5's mega co-residency (two rounds proved foreign resident roles
// inflate the recurrence 4.4x regardless of poll rate). Projections are now
// computed by the LSTM layers' OWN blocks after their recurrence finishes:
// ep (enc layers 0/1, 32 tiles) hides under the decoder phase; dp (dec
// layers 2/3) is a short kernel tail. No long-lived waiters; every POLLCOL
// here is satisfied within ~us (peers finish together).
//
// Sync: v3/v4 data-is-flag (hsync poisoned 0xFFFFFFFF; packed bf16-hi of a
// finite h is never 0xFFFF). Producers: one relaxed agent-scope store.
// Consumers: atomic sentinel polls; plain reads only of lines whose every
// word was polled valid by this block first (first touch this kernel ->
// no stale L2 copy possible; kernel-boundary acquire covers attn_ctx).
// ---------------------------------------------------------------------------

typedef __attribute__((ext_vector_type(8))) short s8v;
typedef __attribute__((ext_vector_type(8))) __bf16 bf8v;
typedef __attribute__((ext_vector_type(4))) float f4v;

#define HDIM 256
#define DLEN 127
#define NVOC 32000
#define SENTINEL 0xFFFFFFFFu

__device__ __forceinline__ float bf2f(unsigned short u) {
  union { unsigned int i; float f; } v; v.i = ((unsigned int)u) << 16; return v.f;
}
__device__ __forceinline__ unsigned short f2bf(float x) {
  union { float f; unsigned int i; } v; v.f = x;
  unsigned int u = v.i;
  return (unsigned short)((u + 0x7FFFu + ((u >> 16) & 1u)) >> 16);
}
__device__ __forceinline__ float sigm(float x) {
  x = fminf(fmaxf(x, -30.f), 30.f);
  return 1.f / (1.f + __expf(-x));
}
__device__ __forceinline__ float tanh_f(float x) {
  float y = fminf(fmaxf(x, -15.f), 15.f);
  float e = __expf(2.f * y);
  return (e - 1.f) / (e + 1.f);
}
__device__ __forceinline__ f4v mfma_bf16(s8v a, s8v b, f4v c) {
  return __builtin_amdgcn_mfma_f32_16x16x32_bf16(
      __builtin_bit_cast(bf8v, a), __builtin_bit_cast(bf8v, b), c, 0, 0, 0);
}

// sentinel column poll: 16 rows x stride-256 words at column tid
#define POLLCOL(base)                                                         \
  for (;;) {                                                                  \
    bool ok = true;                                                           \
    _Pragma("unroll") for (int i_ = 0; i_ < 16; i_++)                         \
        uv[i_] = __hip_atomic_load((base) + i_ * 256 + tid, __ATOMIC_RELAXED, \
                                   __HIP_MEMORY_SCOPE_AGENT);                 \
    _Pragma("unroll") for (int i_ = 0; i_ < 16; i_++)                         \
        ok &= (uv[i_] != SENTINEL);                                           \
    if (ok) break;                                                            \
    __builtin_amdgcn_s_sleep(1);                                              \
  }

// ---------------- fused preprocessing (proven v5) ----------------
// grid 9228: [0,4096) Whh hi/lo split; [4096,8192) Wih bf16; [8192,8208)
// bias sums; [8208,8720) enc gather (4 rows/block); [8720,9228) dec gather.
__global__ __launch_bounds__(256) void prep(
    const float* __restrict__ W5, const float* __restrict__ W9,
    const float* __restrict__ W13, const float* __restrict__ W17,
    const float* __restrict__ W4, const float* __restrict__ W8,
    const float* __restrict__ W12, const float* __restrict__ W16,
    const float* __restrict__ b6, const float* __restrict__ b7,
    const float* __restrict__ b10, const float* __restrict__ b11,
    const float* __restrict__ b14, const float* __restrict__ b15,
    const float* __restrict__ b18, const float* __restrict__ b19,
    const int* __restrict__ src, const int* __restrict__ tgt,
    const float* __restrict__ enc_emb, const float* __restrict__ dec_emb,
    unsigned short* __restrict__ WHB, unsigned short* __restrict__ WIB,
    float* __restrict__ bsum,
    unsigned short* __restrict__ Xe, unsigned short* __restrict__ Xd) {
  int blk = blockIdx.x, tid = threadIdx.x;
  if (blk < 4096) {
    int l = blk >> 10;
    int i = (blk & 1023) * 256 + tid;
    const float* W = (l == 0) ? W5 : (l == 1) ? W9 : (l == 2) ? W13 : W17;
    float w = W[i];
    unsigned short h = f2bf(w);
    unsigned short* Hh = WHB + (size_t)l * 524288;
    Hh[i] = h;
    Hh[262144 + i] = f2bf(w - bf2f(h));
  } else if (blk < 8192) {
    int l = (blk - 4096) >> 10;
    int i = ((blk - 4096) & 1023) * 256 + tid;
    const float* W = (l == 0) ? W4 : (l == 1) ? W8 : (l == 2) ? W12 : W16;
    WIB[(size_t)l * 262144 + i] = f2bf(W[i]);
  } else if (blk < 8208) {
    int i = (blk - 8192) * 256 + tid;
    int l = i >> 10, n = i & 1023;
    const float* bi = (l == 0) ? b6 : (l == 1) ? b10 : (l == 2) ? b14 : b18;
    const float* bh = (l == 0) ? b7 : (l == 1) ? b11 : (l == 2) ? b15 : b19;
    bsum[i] = bi[n] + bh[n];
  } else if (blk < 8720) {
    int r = (blk - 8208) * 4 + (tid >> 6);
    int lane = tid & 63;
    int token = src[r];
    float4 v = *(const float4*)&enc_emb[(size_t)token * HDIM + lane * 4];
    unsigned short q[4] = {f2bf(v.x), f2bf(v.y), f2bf(v.z), f2bf(v.w)};
    *(uint2*)&Xe[(size_t)r * HDIM + lane * 4] = *(uint2*)q;
  } else {
    int r = (blk - 8720) * 4 + (tid >> 6);
    int lane = tid & 63;
    int token = tgt[(r / DLEN) * 128 + (r % DLEN)];
    float4 v = *(const float4*)&dec_emb[(size_t)token * HDIM + lane * 4];
    unsigned short q[4] = {f2bf(v.x), f2bf(v.y), f2bf(v.z), f2bf(v.w)};
    *(uint2*)&Xd[(size_t)r * HDIM + lane * 4] = *(uint2*)q;
  }
}

// ---------------- pipelined 4-layer LSTM + projection epilogues ----------------
// grid 124; worker iff (widx&7)<4: layer=widx&7 (-> XCD l), blk=widx>>3.
// Recurrence identical to v4 (proven 628us). Afterwards each block computes
// one 128x128 projection tile: layers 0/1 -> ep = enc1_h @ We^T (polls hs1);
// layers 2/3 -> dp = dec1_h @ Wd^T + attn_b (polls hs3). Tile q: layer&1==0
// -> q=blk, else q=blk+16; g=q>>1 (8-step row group), n0=(q&1)*128.
__global__ __launch_bounds__(256) void lstm_pipe(
    const unsigned short* __restrict__ WIB,   // [4][1024][256] bf16
    const unsigned short* __restrict__ WHB,   // [4][hi 262144 | lo 262144]
    const float* __restrict__ bsum,           // [4][1024] bih+bhh
    const unsigned short* __restrict__ Xe,    // [16*128][256] bf16
    const unsigned short* __restrict__ Xd,    // [16*127][256] bf16
    unsigned int* __restrict__ hsA,           // [4][Tl][16][256] packed hi|lo
    unsigned int* __restrict__ cfinA,         // [2][4096] fp32 bits, poisoned
    const float* __restrict__ attnW,          // [256][512]
    const float* __restrict__ attnB,          // [256]
    float* __restrict__ dpf,                  // [2032][256] fp32 out
    float* __restrict__ epf,                  // [2048][256] fp32 out
    unsigned short* __restrict__ Acat) {      // [2032][512] cols 0..255
  int widx = (int)blockIdx.x;
  if (widx & 4) return;                       // (widx&7)>=4 -> exit
  int layer = widx & 7;
  if (layer > 3) return;
  int blk = widx >> 3;
  __shared__ unsigned short xx[16 * 264];
  __shared__ unsigned short hh[16 * 264];
  __shared__ unsigned short hl[16 * 264];
  __shared__ float gbuf[4][16][16];
  __shared__ unsigned short As[128 * 40];
  __shared__ unsigned short Bs[128 * 40];
  int tid = threadIdx.x;
  int lane = tid & 63, gate = tid >> 6;
  int U = blk * 16;
  int r16 = lane & 15, kg = lane >> 4;
  int Tl = (layer < 2) ? 128 : 127;
  unsigned int* own = hsA + (size_t)layer * 524288;
  const unsigned int* prevb = (layer & 1) ? own - 524288 : nullptr;
  const unsigned short* Xg = (layer == 0) ? Xe : (layer == 2) ? Xd : nullptr;
  const unsigned int* hini =
      (layer >= 2) ? hsA + (size_t)(layer - 2) * 524288 + (size_t)127 * 4096
                   : nullptr;
  unsigned int* cini = (layer >= 2) ? cfinA + (size_t)(layer - 2) * 4096 : nullptr;
  unsigned int* cout = (layer < 2) ? cfinA + (size_t)layer * 4096 : nullptr;
  unsigned short* hout = (layer == 3) ? Acat : nullptr;

  s8v wfi[8], wfh[8], wfl[8];
  {
    const unsigned short* wi = WIB + (size_t)layer * 262144;
    const unsigned short* wh = WHB + (size_t)layer * 524288;
    const unsigned short* wl = wh + 262144;
    long roff = (long)(gate * 256 + U + r16) * 256 + kg * 8;
    for (int kt = 0; kt < 8; kt++) {
      wfi[kt] = *(const s8v*)(wi + roff + kt * 32);
      wfh[kt] = *(const s8v*)(wh + roff + kt * 32);
      wfl[kt] = *(const s8v*)(wl + roff + kt * 32);
    }
  }
  int b = tid >> 4, u = tid & 15;
  float bb0 = bsum[layer * 1024 + U + u];
  float bb1 = bsum[layer * 1024 + 256 + U + u];
  float bb2 = bsum[layer * 1024 + 512 + U + u];
  float bb3 = bsum[layer * 1024 + 768 + U + u];
  float c;
  if (cini) {
    unsigned int cw;
    for (;;) {
      cw = __hip_atomic_load(cini + b * 256 + U + u, __ATOMIC_RELAXED,
                             __HIP_MEMORY_SCOPE_AGENT);
      if (cw != SENTINEL) break;
      __builtin_amdgcn_s_sleep(8);            // long wait: enc still running
    }
    union { unsigned int i; float f; } cv; cv.i = cw; c = cv.f;
  } else {
    c = 0.f;
  }

  for (int t = 0; t < Tl; t++) {
    unsigned int uv[16];
    unsigned short xr[16];
    if (Xg) {                                  // issue x loads early (no dep)
#pragma unroll
      for (int i = 0; i < 16; i++)
        xr[i] = Xg[((size_t)(i * Tl + t)) * 256 + tid];
    }
    const unsigned int* hbase = (t > 0) ? own + (size_t)(t - 1) * 4096 : hini;
    if (hbase) {
      POLLCOL(hbase)
#pragma unroll
      for (int i = 0; i < 16; i++) {
        hh[i * 264 + tid] = (unsigned short)(uv[i] >> 16);
        hl[i * 264 + tid] = (unsigned short)(uv[i] & 0xFFFFu);
      }
    } else {
#pragma unroll
      for (int i = 0; i < 16; i++) { hh[i * 264 + tid] = 0; hl[i * 264 + tid] = 0; }
    }
    if (Xg) {
#pragma unroll
      for (int i = 0; i < 16; i++) xx[i * 264 + tid] = xr[i];
    } else {
      POLLCOL(prevb + (size_t)t * 4096)
#pragma unroll
      for (int i = 0; i < 16; i++)
        xx[i * 264 + tid] = (unsigned short)(uv[i] >> 16);
    }
    __syncthreads();                           // LDS tiles ready
    f4v a0 = (f4v){0.f, 0.f, 0.f, 0.f};
    f4v a1 = a0, a2 = a0, a3 = a0;
#pragma unroll
    for (int kt = 0; kt < 8; kt++) {
      s8v xv = *(const s8v*)&xx[r16 * 264 + kt * 32 + kg * 8];
      s8v ah = *(const s8v*)&hh[r16 * 264 + kt * 32 + kg * 8];
      s8v al = *(const s8v*)&hl[r16 * 264 + kt * 32 + kg * 8];
      a3 = mfma_bf16(xv, wfi[kt], a3);
      a0 = mfma_bf16(ah, wfh[kt], a0);
      a1 = mfma_bf16(al, wfh[kt], a1);
      a2 = mfma_bf16(ah, wfl[kt], a2);
    }
#pragma unroll
    for (int r = 0; r < 4; r++)
      gbuf[gate][kg * 4 + r][r16] = a0[r] + a1[r] + a2[r] + a3[r];
    __syncthreads();                           // gbuf ready; fences LDS reuse
    float gi = gbuf[0][b][u] + bb0;
    float gf = gbuf[1][b][u] + bb1;
    float gg = gbuf[2][b][u] + bb2;
    float go = gbuf[3][b][u] + bb3;
    c = sigm(gf) * c + sigm(gi) * tanh_f(gg);
    float h = sigm(go) * tanh_f(c);
    unsigned short hb = f2bf(h);
    unsigned int packed =
        ((unsigned int)hb << 16) | (unsigned int)f2bf(h - bf2f(hb));
    __hip_atomic_store(own + (size_t)t * 4096 + b * 256 + U + u, packed,
                       __ATOMIC_RELAXED, __HIP_MEMORY_SCOPE_AGENT);
    if (hout) hout[(size_t)(b * Tl + t) * 512 + U + u] = hb;
  }
  if (cout) {
    union { float f; unsigned int i; } cv; cv.f = c;
    __hip_atomic_store(cout + b * 256 + U + u, cv.i, __ATOMIC_RELAXED,
                       __HIP_MEMORY_SCOPE_AGENT);
  }

  // ======== projection epilogue: one 128x128 tile per block ========
  {
    int isep = (layer < 2) ? 1 : 0;
    int q = (layer & 1) ? (blk + 16) : blk;   // 32 tiles per projection
    int g = q >> 1, n0 = (q & 1) * 128;
    const unsigned int* slab = hsA + (size_t)(isep ? 1 : 3) * 524288;
    int Tp = isep ? 128 : 127;
    const float* Bw = isep ? (attnW + 256) : attnW;   // ldb 512
    float* outb = isep ? epf : dpf;
    // validate every consumed word (peers finish within ~us of us)
    {
      unsigned int uv[16];
      for (int k = 0; k < 8; k++) {
        int tt = g * 8 + k;
        if (tt < Tp) { POLLCOL(slab + (size_t)tt * 4096) }
      }
    }
    __builtin_amdgcn_sched_barrier(0);
    __syncthreads();   // all 256 columns validated before cross-column reads

    int wid = tid >> 6;
    int wm = (wid >> 1) * 64, wn = (wid & 1) * 64;
    f4v acc[4][4];
    for (int i = 0; i < 4; i++)
      for (int j = 0; j < 4; j++) acc[i][j] = (f4v){0.f, 0.f, 0.f, 0.f};

    for (int k0 = 0; k0 < 256; k0 += 32) {
      for (int i = 0; i < 2; i++) {
        int idx = tid + i * 256;
        int row = idx >> 2, kc = (idx & 3) * 8;
        int tt = g * 8 + (row >> 4), bb = row & 15;
        unsigned short qa[8] = {0, 0, 0, 0, 0, 0, 0, 0};
        if (tt < Tp) {
          const unsigned int* wp = slab + (size_t)tt * 4096 + bb * 256 + k0 + kc;
          uint4 w0 = *(const uint4*)wp, w1 = *(const uint4*)(wp + 4);
          qa[0] = (unsigned short)(w0.x >> 16); qa[1] = (unsigned short)(w0.y >> 16);
          qa[2] = (unsigned short)(w0.z >> 16); qa[3] = (unsigned short)(w0.w >> 16);
          qa[4] = (unsigned short)(w1.x >> 16); qa[5] = (unsigned short)(w1.y >> 16);
          qa[6] = (unsigned short)(w1.z >> 16); qa[7] = (unsigned short)(w1.w >> 16);
        }
        *(uint4*)&As[row * 40 + kc] = *(uint4*)qa;
        const float* bp = &Bw[(size_t)(n0 + row) * 512 + k0 + kc];
        float4 b0 = *(const float4*)bp, b1 = *(const float4*)(bp + 4);
        unsigned short qb[8] = {f2bf(b0.x), f2bf(b0.y), f2bf(b0.z), f2bf(b0.w),
                                f2bf(b1.x), f2bf(b1.y), f2bf(b1.z), f2bf(b1.w)};
        *(uint4*)&Bs[row * 40 + kc] = *(uint4*)qb;
      }
      __syncthreads();
      s8v af[4], bfg[4];
      for (int f = 0; f < 4; f++) {
        af[f]  = *(const s8v*)&As[(wm + f * 16 + r16) * 40 + kg * 8];
        bfg[f] = *(const s8v*)&Bs[(wn + f * 16 + r16) * 40 + kg * 8];
      }
      for (int i = 0; i < 4; i++)
        for (int j = 0; j < 4; j++)
          acc[i][j] = mfma_bf16(af[i], bfg[j], acc[i][j]);
      __syncthreads();
    }
    int rbase = kg * 4;
    for (int j = 0; j < 4; j++) {
      int n = n0 + wn + j * 16 + r16;
      float bv = isep ? 0.f : attnB[n];
      for (int i = 0; i < 4; i++) {
        for (int r = 0; r < 4; r++) {
          int m = wm + i * 16 + rbase + r;
          int tt = g * 8 + (m >> 4), bb = m & 15;
          if (tt < Tp) {
            size_t row = isep ? (size_t)(bb * 128 + tt) : (size_t)(bb * DLEN + tt);
            outb[row * 256 + n] = acc[i][j][r] + bv;
          }
        }
      }
    }
  }
}

// ---------------- attention: scores + softmax + context (proven v4) ----------
__global__ __launch_bounds__(256) void attn_ctx(
    const float* __restrict__ dp,             // [2032][256] (includes attn_b)
    const float* __restrict__ ep,             // [2048][256]
    const float* __restrict__ vw,             // [256]
    const unsigned int* __restrict__ enc_out, // [128][16][256] packed hi|lo
    unsigned short* __restrict__ Acat)        // [2032][512], write cols 256..511
{
  __shared__ float sdp[256], sv[256], sc[128];
  int bt = blockIdx.x;
  int b = bt / DLEN;
  int tid = threadIdx.x;
  sdp[tid] = dp[(long)bt * 256 + tid];
  sv[tid] = vw[tid];
  __syncthreads();
  int lane = tid & 63, wid = tid >> 6;
  for (int i = 0; i < 32; i++) {
    int s = wid * 32 + i;
    float4 e4 = *(const float4*)&ep[(long)(b * 128 + s) * 256 + lane * 4];
    int h0 = lane * 4;
    float part = sv[h0] * tanh_f(sdp[h0] + e4.x);
    part += sv[h0 + 1] * tanh_f(sdp[h0 + 1] + e4.y);
    part += sv[h0 + 2] * tanh_f(sdp[h0 + 2] + e4.z);
    part += sv[h0 + 3] * tanh_f(sdp[h0 + 3] + e4.w);
    for (int off = 32; off >= 1; off >>= 1) part += __shfl_xor(part, off);
    if (lane == 0) sc[s] = part;
  }
  __syncthreads();
  if (wid == 0) {
    float a0 = sc[lane], a1 = sc[lane + 64];
    float mx = fmaxf(a0, a1);
    for (int off = 32; off >= 1; off >>= 1) mx = fmaxf(mx, __shfl_xor(mx, off));
    float e0 = __expf(a0 - mx), e1 = __expf(a1 - mx);
    float sm = e0 + e1;
    for (int off = 32; off >= 1; off >>= 1) sm += __shfl_xor(sm, off);
    float inv = 1.0f / sm;
    sc[lane] = e0 * inv;
    sc[lane + 64] = e1 * inv;
  }
  __syncthreads();
  float acc = 0.f;
  for (int s = 0; s < 128; s++) {
    unsigned int uv = enc_out[(long)(s * 16 + b) * 256 + tid];
    float hv = bf2f((unsigned short)(uv >> 16)) +
               bf2f((unsigned short)(uv & 0xFFFFu));
    acc += sc[s] * hv;
  }
  Acat[(long)bt * 512 + 256 + tid] = f2bf(acc);
}

// ---------------- logits GEMM (+ fused zero_t0, proven v5) ----------------
__global__ __launch_bounds__(256) void logits_gemm(
    const unsigned short* __restrict__ A,     // Acat [2032][512] bf16
    const float* __restrict__ B,              // outW [32000][512] fp32
    const float* __restrict__ bias,           // outB
    float* __restrict__ Cf) {                 // out  [16*128][32000]
  int n0 = blockIdx.x * 128;
  int tid = threadIdx.x;
  if (blockIdx.y == 16) {
    int col = tid & 127;
    for (int b = tid >> 7; b < 16; b += 2)
      Cf[(size_t)b * 128 * NVOC + n0 + col] = 0.f;
    return;
  }
  __shared__ unsigned short As[128 * 40];
  __shared__ unsigned short Bs[128 * 40];
  int lane = tid & 63, wid = tid >> 6;
  int wm = (wid >> 1) * 64, wn = (wid & 1) * 64;
  int r16 = lane & 15, kg = lane >> 4;
  int m0 = blockIdx.y * 128;
  f4v acc[4][4];
  for (int i = 0; i < 4; i++)
    for (int j = 0; j < 4; j++) acc[i][j] = (f4v){0.f, 0.f, 0.f, 0.f};

  for (int k0 = 0; k0 < 512; k0 += 32) {
    for (int i = 0; i < 2; i++) {
      int idx = tid + i * 256;
      int row = idx >> 2, kc = (idx & 3) * 8;
      uint4 va = {0u, 0u, 0u, 0u};
      int gm = m0 + row;
      if (gm < 2032) va = *(const uint4*)&A[(size_t)gm * 512 + k0 + kc];
      *(uint4*)&As[row * 40 + kc] = va;
      const float* bp = &B[(size_t)(n0 + row) * 512 + k0 + kc];
      float4 b0 = *(const float4*)bp, b1 = *(const float4*)(bp + 4);
      unsigned short q[8] = {f2bf(b0.x), f2bf(b0.y), f2bf(b0.z), f2bf(b0.w),
                             f2bf(b1.x), f2bf(b1.y), f2bf(b1.z), f2bf(b1.w)};
      *(uint4*)&Bs[row * 40 + kc] = *(uint4*)q;
    }
    __syncthreads();
    s8v af[4], bfg[4];
    for (int f = 0; f < 4; f++) {
      af[f]  = *(const s8v*)&As[(wm + f * 16 + r16) * 40 + kg * 8];
      bfg[f] = *(const s8v*)&Bs[(wn + f * 16 + r16) * 40 + kg * 8];
    }
    for (int i = 0; i < 4; i++)
      for (int j = 0; j < 4; j++)
        acc[i][j] = mfma_bf16(af[i], bfg[j], acc[i][j]);
    __syncthreads();
  }
  int rbase = kg * 4;
  for (int j = 0; j < 4; j++) {
    int n = n0 + wn + j * 16 + r16;
    float bv = bias[n];
    for (int i = 0; i < 4; i++) {
      for (int r = 0; r < 4; r++) {
        int m = m0 + wm + i * 16 + rbase + r;
        if (m < 2032) {
          int bb = m / DLEN, tt = m - bb * DLEN;
          Cf[(size_t)(bb * 128 + tt + 1) * NVOC + n] = acc[i][j][r] + bv;
        }
      }
    }
  }
}

// ---------------------------------------------------------------------------
extern "C" void kernel_launch(void* const* d_in, const int* in_sizes, int n_in,
                              void* d_out, int out_size, void* d_ws, size_t ws_size,
                              hipStream_t stream) {
  (void)in_sizes; (void)n_in; (void)out_size; (void)ws_size;
  const int* src = (const int*)d_in[0];
  const int* tgt = (const int*)d_in[1];
  auto F32 = [&](int i) { return (const float*)d_in[i]; };
  const float* enc_emb = F32(2);
  const float* dec_emb = F32(3);
  const float* attnW = F32(20);
  const float* attnB = F32(21);
  const float* vw = F32(22);
  const float* outW = F32(23);
  const float* outB = F32(24);
  float* out = (float*)d_out;

  // ---- d_out scratch (dead before logits_gemm writes) ----
  // poison region (one memset): hsA | cfinA
  unsigned int* hsA = (unsigned int*)out;                 // 2,097,152 u32
  unsigned int* cfinA = hsA + 2097152;                    // 8,192 u32
  // non-poisoned scratch
  float* dpf = (float*)(cfinA + 8192);                    // 520,192 f
  float* epf = dpf + 520192;                              // 524,288 f
  unsigned short* WHB = (unsigned short*)(epf + 524288);  // 2,097,152 sh
  unsigned short* WIB = WHB + 2097152;                    // 1,048,576 sh
  unsigned short* Xe  = WIB + 1048576;                    // 524,288 sh
  unsigned short* Xd  = Xe + 524288;                      // 520,192 sh
  float* bsum = (float*)(Xd + 520192);                    // 4,096 f
  // total ~21 MB << 262 MB of d_out

  // ---- d_ws: Acat only (live during logits GEMM) ----
  unsigned short* Acat = (unsigned short*)d_ws;           // 2,080,768 B

  size_t poisonB = (size_t)(2097152 + 8192) * 4;
  hipMemsetAsync(hsA, 0xFF, poisonB, stream);
  prep<<<9228, 256, 0, stream>>>(
      F32(5), F32(9), F32(13), F32(17),
      F32(4), F32(8), F32(12), F32(16),
      F32(6), F32(7), F32(10), F32(11),
      F32(14), F32(15), F32(18), F32(19),
      src, tgt, enc_emb, dec_emb,
      WHB, WIB, bsum, Xe, Xd);
  lstm_pipe<<<124, 256, 0, stream>>>(WIB, WHB, bsum, Xe, Xd, hsA, cfinA,
                                     attnW, attnB, dpf, epf, Acat);
  attn_ctx<<<2032, 256, 0, stream>>>(dpf, epf, vw, hsA + 524288, Acat);
  // ---- final writes: every element of d_out overwritten from here ----
  logits_gemm<<<dim3(250, 17), 256, 0, stream>>>(Acat, outW, outB, out);
}